// Round 1
// baseline (760.469 us; speedup 1.0000x reference)
//
#include <hip/hip_runtime.h>
#include <hip/hip_bf16.h>

#define N_NODES 50000
#define N_EDGES 800000
#define NUM_GRAPHS 256
#define D 64
#define EPS 1e-5f

// ---------------------------------------------------------------------------
// 1) degree accumulation: deg[col[e]] += 1  (self-loop added later)
__global__ void deg_kernel(const int* __restrict__ col, float* __restrict__ deg, int E) {
    int i = blockIdx.x * blockDim.x + threadIdx.x;
    if (i < E) atomicAdd(&deg[col[i]], 1.0f);
}

// 2) dinv[n] = 1/sqrt(deg[n] + 1)   (exact via double; deg is small integer)
__global__ void dinv_kernel(float* __restrict__ deg, int N) {
    int i = blockIdx.x * blockDim.x + threadIdx.x;
    if (i < N) {
        double d = (double)deg[i] + 1.0;
        deg[i] = (float)(1.0 / sqrt(d));
    }
}

// 3) Y[N,64] = X[N,64] @ W[64,64]  — W staged in LDS, 16 rows/block/iter,
//    each thread computes 4 rows x 1 col (5 LDS reads / 4 FMA).
__global__ void gemm64_kernel(const float* __restrict__ X, const float* __restrict__ W,
                              float* __restrict__ Y, int N) {
    __shared__ float Ws[64 * 64];
    __shared__ float Xs[16 * 64];
    for (int i = threadIdx.x; i < 64 * 64; i += 256) Ws[i] = W[i];
    int c  = threadIdx.x & 63;
    int rg = threadIdx.x >> 6;  // 0..3 -> rows rg*4 .. rg*4+3 of the 16-row tile
    __syncthreads();
    for (int base = blockIdx.x * 16; base < N; base += gridDim.x * 16) {
        for (int i = threadIdx.x; i < 16 * 64; i += 256) {
            int rr = base + (i >> 6);
            Xs[i] = (rr < N) ? X[rr * 64 + (i & 63)] : 0.0f;
        }
        __syncthreads();
        float a0 = 0.f, a1 = 0.f, a2 = 0.f, a3 = 0.f;
#pragma unroll
        for (int k = 0; k < 64; k++) {
            float w = Ws[k * 64 + c];
            a0 += Xs[(rg * 4 + 0) * 64 + k] * w;
            a1 += Xs[(rg * 4 + 1) * 64 + k] * w;
            a2 += Xs[(rg * 4 + 2) * 64 + k] * w;
            a3 += Xs[(rg * 4 + 3) * 64 + k] * w;
        }
        int r = base + rg * 4;
        if (r + 3 < N) {
            Y[(r + 0) * 64 + c] = a0;
            Y[(r + 1) * 64 + c] = a1;
            Y[(r + 2) * 64 + c] = a2;
            Y[(r + 3) * 64 + c] = a3;
        } else {
            if (r + 0 < N) Y[(r + 0) * 64 + c] = a0;
            if (r + 1 < N) Y[(r + 1) * 64 + c] = a1;
            if (r + 2 < N) Y[(r + 2) * 64 + c] = a2;
            if (r + 3 < N) Y[(r + 3) * 64 + c] = a3;
        }
        __syncthreads();
    }
}

// 4) edge aggregation: dst[col] += dinv[row]*dinv[col] * src[row]  (one wave/edge)
__global__ void agg_kernel(const int* __restrict__ ei, const float* __restrict__ dinv,
                           const float* __restrict__ src, float* __restrict__ dst, int E) {
    int gid    = blockIdx.x * blockDim.x + threadIdx.x;
    int lane   = threadIdx.x & 63;
    int wave   = gid >> 6;
    int nwaves = (gridDim.x * blockDim.x) >> 6;
    for (int e = wave; e < E; e += nwaves) {
        int r = ei[e];
        int c = ei[E + e];
        float w = dinv[r] * dinv[c];
        float v = src[r * 64 + lane] * w;
        atomicAdd(&dst[c * 64 + lane], v);
    }
}

// 5) fused: self-loop term + GCN bias + BN + ReLU
//    out = relu( (agg + dinv^2*xw + b - m) * rsqrt(v+eps) * g + bb )
__global__ void bn_kernel(const float* __restrict__ agg, const float* __restrict__ xw,
                          const float* __restrict__ dinv,
                          const float* __restrict__ b, const float* __restrict__ g,
                          const float* __restrict__ bb, const float* __restrict__ m,
                          const float* __restrict__ var,
                          float* __restrict__ out, int N) {
    int idx = blockIdx.x * blockDim.x + threadIdx.x;
    int total = N * 64;
    if (idx < total) {
        int n = idx >> 6, f = idx & 63;
        float dn = dinv[n];
        float v  = agg[idx] + dn * dn * xw[idx] + b[f];
        float h  = (v - m[f]) * (1.0f / sqrtf(var[f] + EPS)) * g[f] + bb[f];
        out[idx] = h > 0.0f ? h : 0.0f;
    }
}

// 6) global mean-pool accumulation
__global__ void pool_kernel(const float* __restrict__ h, const int* __restrict__ batch,
                            float* __restrict__ psum, float* __restrict__ pcnt, int N) {
    int idx = blockIdx.x * blockDim.x + threadIdx.x;
    int total = N * 64;
    if (idx < total) {
        int n = idx >> 6, f = idx & 63;
        int gg = batch[n];
        atomicAdd(&psum[gg * 64 + f], h[idx]);
        if (f == 0) atomicAdd(&pcnt[gg], 1.0f);
    }
}

// 7) full MLP head for one graph per block
__global__ void head_kernel(const float* __restrict__ psum, const float* __restrict__ pcnt,
                            const float* __restrict__ hW1, const float* __restrict__ hb1,
                            const float* __restrict__ hg1, const float* __restrict__ hbb1,
                            const float* __restrict__ hm1, const float* __restrict__ hv1,
                            const float* __restrict__ hW2, const float* __restrict__ hb2,
                            const float* __restrict__ hg2, const float* __restrict__ hbb2,
                            const float* __restrict__ hm2, const float* __restrict__ hv2,
                            const float* __restrict__ hW3, const float* __restrict__ hb3,
                            const float* __restrict__ hW4, const float* __restrict__ hb4,
                            float* __restrict__ out) {
    __shared__ float pooled[64];
    __shared__ float z1[256];
    __shared__ float z2[128];
    __shared__ float z3[64];
    int g = blockIdx.x;
    int t = threadIdx.x;
    if (t < 64) {
        float cnt = pcnt[g];
        cnt = cnt > 1.0f ? cnt : 1.0f;
        pooled[t] = psum[g * 64 + t] / cnt;
    }
    __syncthreads();
    {   // layer 1: 64 -> 256, BN + relu
        float acc = hb1[t];
#pragma unroll
        for (int k = 0; k < 64; k++) acc += pooled[k] * hW1[k * 256 + t];
        acc = (acc - hm1[t]) * (1.0f / sqrtf(hv1[t] + EPS)) * hg1[t] + hbb1[t];
        z1[t] = acc > 0.0f ? acc : 0.0f;
    }
    __syncthreads();
    if (t < 128) {  // layer 2: 256 -> 128, BN + relu
        float acc = hb2[t];
        for (int k = 0; k < 256; k++) acc += z1[k] * hW2[k * 128 + t];
        acc = (acc - hm2[t]) * (1.0f / sqrtf(hv2[t] + EPS)) * hg2[t] + hbb2[t];
        z2[t] = acc > 0.0f ? acc : 0.0f;
    }
    __syncthreads();
    if (t < 64) {   // layer 3: 128 -> 64, relu
        float acc = hb3[t];
        for (int k = 0; k < 128; k++) acc += z2[k] * hW3[k * 64 + t];
        z3[t] = acc > 0.0f ? acc : 0.0f;
    }
    __syncthreads();
    if (t < 64) {   // layer 4: 64 -> 1, wave reduce (threads 0..63 = wave 0)
        float v = z3[t] * hW4[t];
        for (int off = 32; off > 0; off >>= 1) v += __shfl_down(v, off, 64);
        if (t == 0) out[g] = v + hb4[0];
    }
}

extern "C" void kernel_launch(void* const* d_in, const int* in_sizes, int n_in,
                              void* d_out, int out_size, void* d_ws, size_t ws_size,
                              hipStream_t stream) {
    const float* x    = (const float*)d_in[0];
    const int*   ei   = (const int*)d_in[1];    // [2, E] int32
    const int*   batch = (const int*)d_in[2];
    const float* W0 = (const float*)d_in[3];
    const float* b0 = (const float*)d_in[4];
    const float* g0 = (const float*)d_in[5];
    const float* bb0 = (const float*)d_in[6];
    const float* m0 = (const float*)d_in[7];
    const float* v0 = (const float*)d_in[8];
    const float* W1 = (const float*)d_in[9];
    const float* b1 = (const float*)d_in[10];
    const float* g1 = (const float*)d_in[11];
    const float* bb1 = (const float*)d_in[12];
    const float* m1 = (const float*)d_in[13];
    const float* v1 = (const float*)d_in[14];
    const float* hW1 = (const float*)d_in[15];
    const float* hb1 = (const float*)d_in[16];
    const float* hg1 = (const float*)d_in[17];
    const float* hbb1 = (const float*)d_in[18];
    const float* hm1 = (const float*)d_in[19];
    const float* hv1 = (const float*)d_in[20];
    const float* hW2 = (const float*)d_in[21];
    const float* hb2 = (const float*)d_in[22];
    const float* hg2 = (const float*)d_in[23];
    const float* hbb2 = (const float*)d_in[24];
    const float* hm2 = (const float*)d_in[25];
    const float* hv2 = (const float*)d_in[26];
    const float* hW3 = (const float*)d_in[27];
    const float* hb3 = (const float*)d_in[28];
    const float* hW4 = (const float*)d_in[29];
    const float* hb4 = (const float*)d_in[30];
    float* out = (float*)d_out;

    // workspace layout (floats)
    float* bufA = (float*)d_ws;                     // N*64
    float* bufB = bufA + (size_t)N_NODES * D;       // N*64
    float* dinv = bufB + (size_t)N_NODES * D;       // N   (first used as deg accum)
    float* psum = dinv + N_NODES;                   // 256*64
    float* pcnt = psum + NUM_GRAPHS * D;            // 256

    const int NT = 256;
    // zero: deg + psum + pcnt (contiguous), and bufB (agg0 target)
    hipMemsetAsync(dinv, 0, (size_t)(N_NODES + NUM_GRAPHS * D + NUM_GRAPHS) * 4, stream);
    hipMemsetAsync(bufB, 0, (size_t)N_NODES * D * 4, stream);

    deg_kernel<<<(N_EDGES + NT - 1) / NT, NT, 0, stream>>>(ei + N_EDGES, dinv, N_EDGES);
    dinv_kernel<<<(N_NODES + NT - 1) / NT, NT, 0, stream>>>(dinv, N_NODES);

    // layer 0
    gemm64_kernel<<<1024, NT, 0, stream>>>(x, W0, bufA, N_NODES);
    agg_kernel<<<8192, NT, 0, stream>>>(ei, dinv, bufA, bufB, N_EDGES);
    bn_kernel<<<(N_NODES * D + NT - 1) / NT, NT, 0, stream>>>(bufB, bufA, dinv,
        b0, g0, bb0, m0, v0, bufA, N_NODES);

    // layer 1
    gemm64_kernel<<<1024, NT, 0, stream>>>(bufA, W1, bufB, N_NODES);
    hipMemsetAsync(bufA, 0, (size_t)N_NODES * D * 4, stream);
    agg_kernel<<<8192, NT, 0, stream>>>(ei, dinv, bufB, bufA, N_EDGES);
    bn_kernel<<<(N_NODES * D + NT - 1) / NT, NT, 0, stream>>>(bufA, bufB, dinv,
        b1, g1, bb1, m1, v1, bufB, N_NODES);

    // mean pool + head
    pool_kernel<<<(N_NODES * D + NT - 1) / NT, NT, 0, stream>>>(bufB, batch, psum, pcnt, N_NODES);
    head_kernel<<<NUM_GRAPHS, NT, 0, stream>>>(psum, pcnt,
        hW1, hb1, hg1, hbb1, hm1, hv1,
        hW2, hb2, hg2, hbb2, hm2, hv2,
        hW3, hb3, hW4, hb4, out);
}

// Round 2
// 456.772 us; speedup vs baseline: 1.6649x; 1.6649x over previous
//
#include <hip/hip_runtime.h>
#include <hip/hip_bf16.h>

#define N_NODES 50000
#define N_EDGES 800000
#define NUM_GRAPHS 256
#define D 64
#define EPS 1e-5f

// ---------------------------------------------------------------------------
// 1) in-degree histogram (int): deg[col[e]] += 1
__global__ void deg_kernel(const int* __restrict__ col, int* __restrict__ deg, int E) {
    int i = blockIdx.x * blockDim.x + threadIdx.x;
    if (i < E) atomicAdd(&deg[col[i]], 1);
}

// 2) dinv[n] = 1/sqrt(deg[n] + 1)  (exact small ints; double for safety)
__global__ void dinv_kernel(const int* __restrict__ deg, float* __restrict__ dinv, int N) {
    int i = blockIdx.x * blockDim.x + threadIdx.x;
    if (i < N) {
        double d = (double)deg[i] + 1.0;
        dinv[i] = (float)(1.0 / sqrt(d));
    }
}

// 3) single-block exclusive scan over deg -> rowptr[0..N], cursor[i]=rowptr[i]
__global__ __launch_bounds__(1024) void scan_kernel(const int* __restrict__ deg,
                                                    int* __restrict__ rowptr,
                                                    int* __restrict__ cursor, int N) {
    __shared__ int s[1024];
    int t = threadIdx.x;
    if (t == 0) rowptr[0] = 0;
    int carry = 0;
    for (int base = 0; base < N; base += 1024) {
        int v = (base + t < N) ? deg[base + t] : 0;
        s[t] = v;
        __syncthreads();
        for (int off = 1; off < 1024; off <<= 1) {
            int add = (t >= off) ? s[t - off] : 0;
            __syncthreads();
            s[t] += add;
            __syncthreads();
        }
        int incl = s[t];
        int total = s[1023];
        if (base + t < N) {
            rowptr[base + t + 1] = carry + incl;
            cursor[base + t]     = carry + incl - v;
        }
        carry += total;
        __syncthreads();
    }
}

// 4) scatter edges into CSR-by-destination; precompute dinv[src] weight
__global__ void scatter_kernel(const int* __restrict__ ei, const float* __restrict__ dinv,
                               int* __restrict__ cursor, int* __restrict__ ssrc,
                               float* __restrict__ sw, int E) {
    int e = blockIdx.x * blockDim.x + threadIdx.x;
    if (e < E) {
        int r = ei[e];
        int c = ei[E + e];
        int pos = atomicAdd(&cursor[c], 1);
        ssrc[pos] = r;
        sw[pos]   = dinv[r];
    }
}

// 5) Y[N,64] = X[N,64] @ W[64,64]  — W staged in LDS
__global__ void gemm64_kernel(const float* __restrict__ X, const float* __restrict__ W,
                              float* __restrict__ Y, int N) {
    __shared__ float Ws[64 * 64];
    __shared__ float Xs[16 * 64];
    for (int i = threadIdx.x; i < 64 * 64; i += 256) Ws[i] = W[i];
    int c  = threadIdx.x & 63;
    int rg = threadIdx.x >> 6;
    __syncthreads();
    for (int base = blockIdx.x * 16; base < N; base += gridDim.x * 16) {
        for (int i = threadIdx.x; i < 16 * 64; i += 256) {
            int rr = base + (i >> 6);
            Xs[i] = (rr < N) ? X[rr * 64 + (i & 63)] : 0.0f;
        }
        __syncthreads();
        float a0 = 0.f, a1 = 0.f, a2 = 0.f, a3 = 0.f;
#pragma unroll
        for (int k = 0; k < 64; k++) {
            float w = Ws[k * 64 + c];
            a0 += Xs[(rg * 4 + 0) * 64 + k] * w;
            a1 += Xs[(rg * 4 + 1) * 64 + k] * w;
            a2 += Xs[(rg * 4 + 2) * 64 + k] * w;
            a3 += Xs[(rg * 4 + 3) * 64 + k] * w;
        }
        int r = base + rg * 4;
        if (r + 3 < N) {
            Y[(r + 0) * 64 + c] = a0;
            Y[(r + 1) * 64 + c] = a1;
            Y[(r + 2) * 64 + c] = a2;
            Y[(r + 3) * 64 + c] = a3;
        } else {
            if (r + 0 < N) Y[(r + 0) * 64 + c] = a0;
            if (r + 1 < N) Y[(r + 1) * 64 + c] = a1;
            if (r + 2 < N) Y[(r + 2) * 64 + c] = a2;
            if (r + 3 < N) Y[(r + 3) * 64 + c] = a3;
        }
        __syncthreads();
    }
}

// 6) fused CSR aggregation + self-loop + gcn bias + BN + ReLU.
//    One wave per destination node; lane = feature.
//    out[c] = relu( BN( dinv[c] * ( dinv[c]*xw[c] + sum_e sw[e]*xw[ssrc[e]] ) + b ) )
__global__ __launch_bounds__(256) void agg_bn_kernel(
        const float* __restrict__ xw, const int* __restrict__ rowptr,
        const int* __restrict__ ssrc, const float* __restrict__ sw,
        const float* __restrict__ dinv,
        const float* __restrict__ b, const float* __restrict__ g,
        const float* __restrict__ bb, const float* __restrict__ m,
        const float* __restrict__ var,
        float* __restrict__ out, int N) {
    int wave = (blockIdx.x * blockDim.x + threadIdx.x) >> 6;
    int lane = threadIdx.x & 63;
    if (wave >= N) return;
    int c = wave;
    int s0 = rowptr[c], s1 = rowptr[c + 1];
    float dc = dinv[c];
    float acc0 = dc * xw[(size_t)c * 64 + lane];  // self-loop (before final *dc)
    float acc1 = 0.0f;
    int e = s0;
    for (; e + 4 <= s1; e += 4) {
        int   r0 = ssrc[e + 0], r1 = ssrc[e + 1], r2 = ssrc[e + 2], r3 = ssrc[e + 3];
        float w0 = sw[e + 0],  w1 = sw[e + 1],  w2 = sw[e + 2],  w3 = sw[e + 3];
        acc0 += w0 * xw[(size_t)r0 * 64 + lane];
        acc1 += w1 * xw[(size_t)r1 * 64 + lane];
        acc0 += w2 * xw[(size_t)r2 * 64 + lane];
        acc1 += w3 * xw[(size_t)r3 * 64 + lane];
    }
    for (; e < s1; e++) {
        acc0 += sw[e] * xw[(size_t)ssrc[e] * 64 + lane];
    }
    float acc = (acc0 + acc1) * dc + b[lane];
    float h = (acc - m[lane]) * (1.0f / sqrtf(var[lane] + EPS)) * g[lane] + bb[lane];
    out[(size_t)c * 64 + lane] = h > 0.0f ? h : 0.0f;
}

// 7) fused mean-pool (via sorted-batch binary search) + full MLP head.
//    One block (256 thr) per graph.
__global__ __launch_bounds__(256) void pool_head_kernel(
        const float* __restrict__ h, const int* __restrict__ batch,
        const float* __restrict__ hW1, const float* __restrict__ hb1,
        const float* __restrict__ hg1, const float* __restrict__ hbb1,
        const float* __restrict__ hm1, const float* __restrict__ hv1,
        const float* __restrict__ hW2, const float* __restrict__ hb2,
        const float* __restrict__ hg2, const float* __restrict__ hbb2,
        const float* __restrict__ hm2, const float* __restrict__ hv2,
        const float* __restrict__ hW3, const float* __restrict__ hb3,
        const float* __restrict__ hW4, const float* __restrict__ hb4,
        float* __restrict__ out) {
    __shared__ int se[2];
    __shared__ float red[256];
    __shared__ float pooled[64];
    __shared__ float z1[256];
    __shared__ float z2[128];
    __shared__ float z3[64];
    int g = blockIdx.x;
    int t = threadIdx.x;
    if (t < 2) {  // lower_bound(batch, g) and lower_bound(batch, g+1)
        int target = g + t;
        int lo = 0, hi = N_NODES;
        while (lo < hi) {
            int mid = (lo + hi) >> 1;
            if (batch[mid] < target) lo = mid + 1; else hi = mid;
        }
        se[t] = lo;
    }
    __syncthreads();
    int start = se[0], end = se[1];
    {   // mean pool: 4 row-groups x 64 features
        int f = t & 63, rg = t >> 6;
        float part = 0.0f;
        for (int r = start + rg; r < end; r += 4) part += h[(size_t)r * 64 + f];
        red[t] = part;
        __syncthreads();
        if (t < 64) {
            float s = red[t] + red[t + 64] + red[t + 128] + red[t + 192];
            float cnt = (float)(end - start);
            cnt = cnt > 1.0f ? cnt : 1.0f;
            pooled[t] = s / cnt;
        }
    }
    __syncthreads();
    {   // layer 1: 64 -> 256, BN + relu
        float acc = hb1[t];
#pragma unroll
        for (int k = 0; k < 64; k++) acc += pooled[k] * hW1[k * 256 + t];
        acc = (acc - hm1[t]) * (1.0f / sqrtf(hv1[t] + EPS)) * hg1[t] + hbb1[t];
        z1[t] = acc > 0.0f ? acc : 0.0f;
    }
    __syncthreads();
    if (t < 128) {  // layer 2: 256 -> 128, BN + relu
        float acc = hb2[t];
#pragma unroll 8
        for (int k = 0; k < 256; k++) acc += z1[k] * hW2[k * 128 + t];
        acc = (acc - hm2[t]) * (1.0f / sqrtf(hv2[t] + EPS)) * hg2[t] + hbb2[t];
        z2[t] = acc > 0.0f ? acc : 0.0f;
    }
    __syncthreads();
    if (t < 64) {   // layer 3: 128 -> 64, relu
        float acc = hb3[t];
#pragma unroll 8
        for (int k = 0; k < 128; k++) acc += z2[k] * hW3[k * 64 + t];
        z3[t] = acc > 0.0f ? acc : 0.0f;
    }
    __syncthreads();
    if (t < 64) {   // layer 4: 64 -> 1, wave reduce
        float v = z3[t] * hW4[t];
        for (int off = 32; off > 0; off >>= 1) v += __shfl_down(v, off, 64);
        if (t == 0) out[g] = v + hb4[0];
    }
}

extern "C" void kernel_launch(void* const* d_in, const int* in_sizes, int n_in,
                              void* d_out, int out_size, void* d_ws, size_t ws_size,
                              hipStream_t stream) {
    const float* x     = (const float*)d_in[0];
    const int*   ei    = (const int*)d_in[1];   // [2, E] int32
    const int*   batch = (const int*)d_in[2];
    const float* W0 = (const float*)d_in[3];
    const float* b0 = (const float*)d_in[4];
    const float* g0 = (const float*)d_in[5];
    const float* bb0 = (const float*)d_in[6];
    const float* m0 = (const float*)d_in[7];
    const float* v0 = (const float*)d_in[8];
    const float* W1 = (const float*)d_in[9];
    const float* b1 = (const float*)d_in[10];
    const float* g1 = (const float*)d_in[11];
    const float* bb1 = (const float*)d_in[12];
    const float* m1 = (const float*)d_in[13];
    const float* v1 = (const float*)d_in[14];
    const float* hW1 = (const float*)d_in[15];
    const float* hb1 = (const float*)d_in[16];
    const float* hg1 = (const float*)d_in[17];
    const float* hbb1 = (const float*)d_in[18];
    const float* hm1 = (const float*)d_in[19];
    const float* hv1 = (const float*)d_in[20];
    const float* hW2 = (const float*)d_in[21];
    const float* hb2 = (const float*)d_in[22];
    const float* hg2 = (const float*)d_in[23];
    const float* hbb2 = (const float*)d_in[24];
    const float* hm2 = (const float*)d_in[25];
    const float* hv2 = (const float*)d_in[26];
    const float* hW3 = (const float*)d_in[27];
    const float* hb3 = (const float*)d_in[28];
    const float* hW4 = (const float*)d_in[29];
    const float* hb4 = (const float*)d_in[30];
    float* out = (float*)d_out;

    // workspace layout (4-byte elements)
    float* bufA   = (float*)d_ws;                        // N*64
    float* bufB   = bufA + (size_t)N_NODES * D;          // N*64
    float* dinv   = bufB + (size_t)N_NODES * D;          // N
    int*   deg    = (int*)(dinv + N_NODES);              // N
    int*   rowptr = deg + N_NODES;                       // N+1
    int*   cursor = rowptr + (N_NODES + 1);              // N
    int*   ssrc   = cursor + N_NODES;                    // E
    float* sw     = (float*)(ssrc + N_EDGES);            // E

    const int NT = 256;
    hipMemsetAsync(deg, 0, (size_t)N_NODES * 4, stream);

    // CSR build (once per call; reused by both layers)
    deg_kernel<<<(N_EDGES + NT - 1) / NT, NT, 0, stream>>>(ei + N_EDGES, deg, N_EDGES);
    dinv_kernel<<<(N_NODES + NT - 1) / NT, NT, 0, stream>>>(deg, dinv, N_NODES);
    scan_kernel<<<1, 1024, 0, stream>>>(deg, rowptr, cursor, N_NODES);
    scatter_kernel<<<(N_EDGES + NT - 1) / NT, NT, 0, stream>>>(ei, dinv, cursor, ssrc, sw, N_EDGES);

    // layer 0
    gemm64_kernel<<<1024, NT, 0, stream>>>(x, W0, bufA, N_NODES);
    agg_bn_kernel<<<(N_NODES * 64 + NT - 1) / NT, NT, 0, stream>>>(
        bufA, rowptr, ssrc, sw, dinv, b0, g0, bb0, m0, v0, bufB, N_NODES);

    // layer 1
    gemm64_kernel<<<1024, NT, 0, stream>>>(bufB, W1, bufA, N_NODES);
    agg_bn_kernel<<<(N_NODES * 64 + NT - 1) / NT, NT, 0, stream>>>(
        bufA, rowptr, ssrc, sw, dinv, b1, g1, bb1, m1, v1, bufB, N_NODES);

    // mean pool + MLP head (fused)
    pool_head_kernel<<<NUM_GRAPHS, NT, 0, stream>>>(bufB, batch,
        hW1, hb1, hg1, hbb1, hm1, hv1,
        hW2, hb2, hg2, hbb2, hm2, hv2,
        hW3, hb3, hW4, hb4, out);
}

// Round 3
// 367.102 us; speedup vs baseline: 2.0715x; 1.2443x over previous
//
#include <hip/hip_runtime.h>
#include <hip/hip_bf16.h>

#define N_NODES 50000
#define N_EDGES 800000
#define NUM_GRAPHS 256
#define D 64
#define EPS 1e-5f
#define SCAN_NB ((N_NODES + 1023) / 1024)   // 49

// ---------------------------------------------------------------------------
// 1) in-degree histogram (int): deg[col[e]] += 1
__global__ void deg_kernel(const int* __restrict__ col, int* __restrict__ deg, int E) {
    int i = blockIdx.x * blockDim.x + threadIdx.x;
    if (i < E) atomicAdd(&deg[col[i]], 1);
}

// 2) dinv[n] = 1/sqrt(deg[n] + 1)  (exact small ints; double for safety)
__global__ void dinv_kernel(const int* __restrict__ deg, float* __restrict__ dinv, int N) {
    int i = blockIdx.x * blockDim.x + threadIdx.x;
    if (i < N) {
        double d = (double)deg[i] + 1.0;
        dinv[i] = (float)(1.0 / sqrt(d));
    }
}

// 3a) per-chunk inclusive scan (1024-elem chunks)
__global__ __launch_bounds__(1024) void scan_local_kernel(const int* __restrict__ deg,
                                                          int* __restrict__ lscan,
                                                          int* __restrict__ bsum, int N) {
    __shared__ int s[1024];
    int t = threadIdx.x;
    int i = blockIdx.x * 1024 + t;
    int v = (i < N) ? deg[i] : 0;
    s[t] = v;
    __syncthreads();
    for (int off = 1; off < 1024; off <<= 1) {
        int add = (t >= off) ? s[t - off] : 0;
        __syncthreads();
        s[t] += add;
        __syncthreads();
    }
    if (i < N) lscan[i] = s[t];
    if (t == 1023) bsum[blockIdx.x] = s[1023];
}

// 3b) exclusive scan of the 49 block sums (one wave)
__global__ void scan_bsum_kernel(const int* __restrict__ bsum, int* __restrict__ boff, int NB) {
    int t = threadIdx.x;  // 64 threads
    int v = (t < NB) ? bsum[t] : 0;
    int x = v;
    for (int off = 1; off < 64; off <<= 1) {
        int y = __shfl_up(x, off, 64);
        if (t >= off) x += y;
    }
    if (t < NB) boff[t] = x - v;  // exclusive
}

// 3c) finalize rowptr + cursor
__global__ __launch_bounds__(1024) void scan_final_kernel(const int* __restrict__ deg,
                                                          const int* __restrict__ lscan,
                                                          const int* __restrict__ boff,
                                                          int* __restrict__ rowptr,
                                                          int* __restrict__ cursor, int N) {
    int i = blockIdx.x * 1024 + threadIdx.x;
    if (i == 0) rowptr[0] = 0;
    if (i < N) {
        int incl = lscan[i] + boff[blockIdx.x];
        rowptr[i + 1] = incl;
        cursor[i]     = incl - deg[i];
    }
}

// 4) scatter edges into CSR-by-destination; precompute dinv[src] weight
__global__ void scatter_kernel(const int* __restrict__ ei, const float* __restrict__ dinv,
                               int* __restrict__ cursor, int* __restrict__ ssrc,
                               float* __restrict__ sw, int E) {
    int e = blockIdx.x * blockDim.x + threadIdx.x;
    if (e < E) {
        int r = ei[e];
        int c = ei[E + e];
        int pos = atomicAdd(&cursor[c], 1);
        ssrc[pos] = r;
        sw[pos]   = dinv[r];
    }
}

// 5) Y[N,64] = X[N,64] @ W[64,64]  — one 16-row tile per block.
//    thread = (row 0..15, colgroup 0..15 of 4 cols). W float4 reads, X broadcast
//    from +1-padded LDS, float4 output store.
__global__ __launch_bounds__(256) void gemm64_kernel(const float* __restrict__ X,
                                                     const float* __restrict__ W,
                                                     float* __restrict__ Y, int N) {
    __shared__ float Ws[64 * 64];
    __shared__ float Xs[16 * 65];
    for (int i = threadIdx.x; i < 1024; i += 256)
        ((float4*)Ws)[i] = ((const float4*)W)[i];
    int cg  = (threadIdx.x & 15) * 4;
    int row = threadIdx.x >> 4;
    int base = blockIdx.x * 16;
    {   // stage X tile: thread i loads one float4
        int i  = threadIdx.x;
        int rr = i >> 4, cc = (i & 15) * 4;
        float4 xv = (base + rr < N)
            ? ((const float4*)X)[(size_t)(base + rr) * 16 + (i & 15)]
            : make_float4(0.f, 0.f, 0.f, 0.f);
        float* dst = &Xs[rr * 65 + cc];
        dst[0] = xv.x; dst[1] = xv.y; dst[2] = xv.z; dst[3] = xv.w;
    }
    __syncthreads();
    float4 acc = make_float4(0.f, 0.f, 0.f, 0.f);
#pragma unroll
    for (int k = 0; k < 64; k++) {
        float  xv = Xs[row * 65 + k];
        float4 wv = *(const float4*)&Ws[k * 64 + cg];
        acc.x += xv * wv.x; acc.y += xv * wv.y;
        acc.z += xv * wv.z; acc.w += xv * wv.w;
    }
    if (base + row < N)
        *((float4*)&Y[(size_t)(base + row) * 64 + cg]) = acc;
}

// 6) fused CSR aggregation + self-loop + gcn bias + BN + ReLU.
//    One wave per destination node; lane = feature.
__global__ __launch_bounds__(256) void agg_bn_kernel(
        const float* __restrict__ xw, const int* __restrict__ rowptr,
        const int* __restrict__ ssrc, const float* __restrict__ sw,
        const float* __restrict__ dinv,
        const float* __restrict__ b, const float* __restrict__ g,
        const float* __restrict__ bb, const float* __restrict__ m,
        const float* __restrict__ var,
        float* __restrict__ out, int N) {
    int wave = (blockIdx.x * blockDim.x + threadIdx.x) >> 6;
    int lane = threadIdx.x & 63;
    if (wave >= N) return;
    int c = wave;
    int s0 = rowptr[c], s1 = rowptr[c + 1];
    float dc = dinv[c];
    float acc0 = dc * xw[(size_t)c * 64 + lane];  // self-loop (before final *dc)
    float acc1 = 0.0f;
    int e = s0;
    for (; e + 4 <= s1; e += 4) {
        int   r0 = ssrc[e + 0], r1 = ssrc[e + 1], r2 = ssrc[e + 2], r3 = ssrc[e + 3];
        float w0 = sw[e + 0],  w1 = sw[e + 1],  w2 = sw[e + 2],  w3 = sw[e + 3];
        acc0 += w0 * xw[(size_t)r0 * 64 + lane];
        acc1 += w1 * xw[(size_t)r1 * 64 + lane];
        acc0 += w2 * xw[(size_t)r2 * 64 + lane];
        acc1 += w3 * xw[(size_t)r3 * 64 + lane];
    }
    for (; e < s1; e++) {
        acc0 += sw[e] * xw[(size_t)ssrc[e] * 64 + lane];
    }
    float acc = (acc0 + acc1) * dc + b[lane];
    float h = (acc - m[lane]) * (1.0f / sqrtf(var[lane] + EPS)) * g[lane] + bb[lane];
    out[(size_t)c * 64 + lane] = h > 0.0f ? h : 0.0f;
}

// 7) fused mean-pool (via sorted-batch binary search) + full MLP head.
__global__ __launch_bounds__(256) void pool_head_kernel(
        const float* __restrict__ h, const int* __restrict__ batch,
        const float* __restrict__ hW1, const float* __restrict__ hb1,
        const float* __restrict__ hg1, const float* __restrict__ hbb1,
        const float* __restrict__ hm1, const float* __restrict__ hv1,
        const float* __restrict__ hW2, const float* __restrict__ hb2,
        const float* __restrict__ hg2, const float* __restrict__ hbb2,
        const float* __restrict__ hm2, const float* __restrict__ hv2,
        const float* __restrict__ hW3, const float* __restrict__ hb3,
        const float* __restrict__ hW4, const float* __restrict__ hb4,
        float* __restrict__ out) {
    __shared__ int se[2];
    __shared__ float red[256];
    __shared__ float pooled[64];
    __shared__ float z1[256];
    __shared__ float z2[128];
    __shared__ float z3[64];
    int g = blockIdx.x;
    int t = threadIdx.x;
    if (t < 2) {
        int target = g + t;
        int lo = 0, hi = N_NODES;
        while (lo < hi) {
            int mid = (lo + hi) >> 1;
            if (batch[mid] < target) lo = mid + 1; else hi = mid;
        }
        se[t] = lo;
    }
    __syncthreads();
    int start = se[0], end = se[1];
    {   // mean pool: 4 row-groups x 64 features
        int f = t & 63, rg = t >> 6;
        float part = 0.0f;
        for (int r = start + rg; r < end; r += 4) part += h[(size_t)r * 64 + f];
        red[t] = part;
        __syncthreads();
        if (t < 64) {
            float s = red[t] + red[t + 64] + red[t + 128] + red[t + 192];
            float cnt = (float)(end - start);
            cnt = cnt > 1.0f ? cnt : 1.0f;
            pooled[t] = s / cnt;
        }
    }
    __syncthreads();
    {   // layer 1: 64 -> 256, BN + relu
        float acc = hb1[t];
#pragma unroll
        for (int k = 0; k < 64; k++) acc += pooled[k] * hW1[k * 256 + t];
        acc = (acc - hm1[t]) * (1.0f / sqrtf(hv1[t] + EPS)) * hg1[t] + hbb1[t];
        z1[t] = acc > 0.0f ? acc : 0.0f;
    }
    __syncthreads();
    if (t < 128) {  // layer 2: 256 -> 128, BN + relu
        float acc = hb2[t];
#pragma unroll 8
        for (int k = 0; k < 256; k++) acc += z1[k] * hW2[k * 128 + t];
        acc = (acc - hm2[t]) * (1.0f / sqrtf(hv2[t] + EPS)) * hg2[t] + hbb2[t];
        z2[t] = acc > 0.0f ? acc : 0.0f;
    }
    __syncthreads();
    if (t < 64) {   // layer 3: 128 -> 64, relu
        float acc = hb3[t];
#pragma unroll 8
        for (int k = 0; k < 128; k++) acc += z2[k] * hW3[k * 64 + t];
        z3[t] = acc > 0.0f ? acc : 0.0f;
    }
    __syncthreads();
    if (t < 64) {   // layer 4: 64 -> 1, wave reduce
        float v = z3[t] * hW4[t];
        for (int off = 32; off > 0; off >>= 1) v += __shfl_down(v, off, 64);
        if (t == 0) out[g] = v + hb4[0];
    }
}

extern "C" void kernel_launch(void* const* d_in, const int* in_sizes, int n_in,
                              void* d_out, int out_size, void* d_ws, size_t ws_size,
                              hipStream_t stream) {
    const float* x     = (const float*)d_in[0];
    const int*   ei    = (const int*)d_in[1];   // [2, E] int32
    const int*   batch = (const int*)d_in[2];
    const float* W0 = (const float*)d_in[3];
    const float* b0 = (const float*)d_in[4];
    const float* g0 = (const float*)d_in[5];
    const float* bb0 = (const float*)d_in[6];
    const float* m0 = (const float*)d_in[7];
    const float* v0 = (const float*)d_in[8];
    const float* W1 = (const float*)d_in[9];
    const float* b1 = (const float*)d_in[10];
    const float* g1 = (const float*)d_in[11];
    const float* bb1 = (const float*)d_in[12];
    const float* m1 = (const float*)d_in[13];
    const float* v1 = (const float*)d_in[14];
    const float* hW1 = (const float*)d_in[15];
    const float* hb1 = (const float*)d_in[16];
    const float* hg1 = (const float*)d_in[17];
    const float* hbb1 = (const float*)d_in[18];
    const float* hm1 = (const float*)d_in[19];
    const float* hv1 = (const float*)d_in[20];
    const float* hW2 = (const float*)d_in[21];
    const float* hb2 = (const float*)d_in[22];
    const float* hg2 = (const float*)d_in[23];
    const float* hbb2 = (const float*)d_in[24];
    const float* hm2 = (const float*)d_in[25];
    const float* hv2 = (const float*)d_in[26];
    const float* hW3 = (const float*)d_in[27];
    const float* hb3 = (const float*)d_in[28];
    const float* hW4 = (const float*)d_in[29];
    const float* hb4 = (const float*)d_in[30];
    float* out = (float*)d_out;

    // workspace layout (4-byte elements)
    float* bufA   = (float*)d_ws;                        // N*64
    float* bufB   = bufA + (size_t)N_NODES * D;          // N*64
    float* dinv   = bufB + (size_t)N_NODES * D;          // N
    int*   deg    = (int*)(dinv + N_NODES);              // N
    int*   rowptr = deg + N_NODES;                       // N+1
    int*   cursor = rowptr + (N_NODES + 1);              // N
    int*   ssrc   = cursor + N_NODES;                    // E
    float* sw     = (float*)(ssrc + N_EDGES);            // E
    int*   lscan  = (int*)(sw + N_EDGES);                // N
    int*   bsum   = lscan + N_NODES;                     // 64
    int*   boff   = bsum + 64;                           // 64

    const int NT = 256;
    hipMemsetAsync(deg, 0, (size_t)N_NODES * 4, stream);

    // CSR build (once per call; reused by both layers)
    deg_kernel<<<(N_EDGES + NT - 1) / NT, NT, 0, stream>>>(ei + N_EDGES, deg, N_EDGES);
    dinv_kernel<<<(N_NODES + NT - 1) / NT, NT, 0, stream>>>(deg, dinv, N_NODES);
    scan_local_kernel<<<SCAN_NB, 1024, 0, stream>>>(deg, lscan, bsum, N_NODES);
    scan_bsum_kernel<<<1, 64, 0, stream>>>(bsum, boff, SCAN_NB);
    scan_final_kernel<<<SCAN_NB, 1024, 0, stream>>>(deg, lscan, boff, rowptr, cursor, N_NODES);
    scatter_kernel<<<(N_EDGES + NT - 1) / NT, NT, 0, stream>>>(ei, dinv, cursor, ssrc, sw, N_EDGES);

    // layer 0
    gemm64_kernel<<<(N_NODES + 15) / 16, NT, 0, stream>>>(x, W0, bufA, N_NODES);
    agg_bn_kernel<<<(N_NODES * 64 + NT - 1) / NT, NT, 0, stream>>>(
        bufA, rowptr, ssrc, sw, dinv, b0, g0, bb0, m0, v0, bufB, N_NODES);

    // layer 1
    gemm64_kernel<<<(N_NODES + 15) / 16, NT, 0, stream>>>(bufB, W1, bufA, N_NODES);
    agg_bn_kernel<<<(N_NODES * 64 + NT - 1) / NT, NT, 0, stream>>>(
        bufA, rowptr, ssrc, sw, dinv, b1, g1, bb1, m1, v1, bufB, N_NODES);

    // mean pool + MLP head (fused)
    pool_head_kernel<<<NUM_GRAPHS, NT, 0, stream>>>(bufB, batch,
        hW1, hb1, hg1, hbb1, hm1, hv1,
        hW2, hb2, hg2, hbb2, hm2, hv2,
        hW3, hb3, hW4, hb4, out);
}